// Round 1
// baseline (230.355 us; speedup 1.0000x reference)
//
#include <hip/hip_runtime.h>
#include <math.h>

typedef unsigned short u16;
typedef short s16x8 __attribute__((ext_vector_type(8)));
typedef float f32x4 __attribute__((ext_vector_type(4)));
typedef u16 u16x4 __attribute__((ext_vector_type(4)));

#define DEVI __device__ __forceinline__

DEVI u16 f2bf(float f) {
  unsigned u = __builtin_bit_cast(unsigned, f);
  u += 0x7fffu + ((u >> 16) & 1u);
  return (u16)(u >> 16);
}

DEVI f32x4 zero4() { f32x4 z; z[0]=0.f; z[1]=0.f; z[2]=0.f; z[3]=0.f; return z; }

#define MFMA16(a,b,c) __builtin_amdgcn_mfma_f32_16x16x32_bf16((a),(b),(c),0,0,0)

#define GLD16(gp, lp) __builtin_amdgcn_global_load_lds( \
  (const __attribute__((address_space(1))) void*)(const void*)(gp), \
  (__attribute__((address_space(3))) void*)(void*)(lp), 16, 0, 0)

// ---------------------------------------------------------------- prep kernels

__global__ __launch_bounds__(256) void prep_x(const float* __restrict__ x,
                                              u16* __restrict__ Aaug) {
  const int i = blockIdx.x * 256 + threadIdx.x;
  if (i >= 8192 * 192) return;
  const int row = i / 192, c4 = (i - row * 192) * 4;
  const float4 v = *(const float4*)(x + (size_t)row * 768 + c4);
  u16x4 o; o[0]=f2bf(v.x); o[1]=f2bf(v.y); o[2]=f2bf(v.z); o[3]=f2bf(v.w);
  *(u16x4*)(Aaug + (size_t)row * 896 + c4) = o;
}

__global__ __launch_bounds__(256) void prep_w(
    const float* __restrict__ Wqkv, const float* __restrict__ s1,
    const float* __restrict__ Wb, const float* __restrict__ Wup,
    const float* __restrict__ Wa, const float* __restrict__ Wdn,
    const float* __restrict__ Wr, const float* __restrict__ Wp,
    u16* __restrict__ Baug, u16* __restrict__ Wsm, u16* __restrict__ Wpj) {
  const int i = blockIdx.x * 256 + threadIdx.x;
  const int N1 = 2304 * 896, N2 = N1 + 256 * 768, N3 = N2 + 768 * 768;
  if (i < N1) {
    const int c = i / 896, kk = i - c * 896;
    float v;
    if (kk < 768)      v = Wqkv[(size_t)c * 768 + kk] * s1[c];
    else if (kk < 832) v = Wb[(size_t)c * 64 + (kk - 768)];
    else               v = Wup[(size_t)c * 64 + (kk - 832)];
    Baug[i] = f2bf(v);
  } else if (i < N2) {
    const int j = i - N1; const int r = j / 768, kk = j - r * 768;
    float v = 0.0f;
    if (r < 64)       v = Wa[(size_t)r * 768 + kk];
    else if (r < 128) v = Wdn[(size_t)(r - 64) * 768 + kk];
    else if (r < 200) v = Wr[(size_t)(r - 128) * 768 + kk];
    Wsm[j] = f2bf(v);
  } else if (i < N3) {
    const int j = i - N2;
    Wpj[j] = f2bf(Wp[j]);
  }
}

// ---------------------------------------------------------------- GEMM kernel
// MODE 0: small (A_aug x * [Wa;Wad_down;Wrouter]^T), epilogue gelu/sigmoid
// MODE 1: proj  (attn_out * Wproj^T) + bias, SSF2 -> f32 out
// MODE 2: qkv   (A_aug * B_aug^T), phased K with gate scaling, writes q/k/vT

template <int MODE>
__global__ __launch_bounds__(256)
void gemm_mfma(const u16* __restrict__ A, int lda,
               const u16* __restrict__ Bt, int ldb,
               const float* __restrict__ p0, const float* __restrict__ p1,
               const float* __restrict__ p2,
               u16* __restrict__ ob0, u16* __restrict__ ob1, u16* __restrict__ ob2,
               float* __restrict__ of0,
               const float* __restrict__ gates) {
  __shared__ __align__(16) u16 lds[2][8192];     // [buf][A 4096 | B 4096]
  __shared__ float glds[2][2][128];              // [colgroup][gl/gp][row] (MODE2)
  const int tid = threadIdx.x;
  const int w = tid >> 6, l = tid & 63;
  const int rl = l & 15, gq = l >> 4;
  const int wrow = (w >> 1) * 64, wcol = (w & 1) * 64;
  const int br = blockIdx.x, bc = blockIdx.y;
  const int nt = (MODE == 2) ? 28 : 24;

  // staging: wave w stages A rows [w*32,w*32+32), B rows likewise, 16B/lane
  const int srow = l >> 2;                       // row within 16-row chunk
  const int sslot = (l & 3) ^ ((srow >> 1) & 3); // pre-swizzled source slot
  const u16* aSrc = A + (size_t)(br * 128 + w * 32 + srow) * lda + sslot * 8;
  const u16* bSrc = Bt + (size_t)(bc * 128 + w * 32 + srow) * ldb + sslot * 8;

  int tq = 0;
  if constexpr (MODE == 2) {
    const int g = bc * 2 + (w & 1);
    tq = g / 12;
    {
      const int gsel = tid >> 7, rr = tid & 127;
      const int gg = bc * 2 + gsel;
      const int tt = gg / 12, hh = gg % 12;
      const int f = hh * 3 + tt;
      const int ridx = (f / 12) * 24 + (f % 12) * 2;
      glds[gsel][0][rr] = gates[(size_t)(br * 128 + rr) * 72 + ridx];
      glds[gsel][1][rr] = gates[(size_t)(br * 128 + rr) * 72 + ridx + 1];
    }
  }

  f32x4 acc[4][4];
#pragma unroll
  for (int i = 0; i < 4; ++i)
#pragma unroll
    for (int j = 0; j < 4; ++j) acc[i][j] = zero4();

  auto kt_of = [&](int t) {
    if constexpr (MODE == 2) return (t < 2) ? 26 + t : ((t < 4) ? 22 + t : t - 4);
    else return t;
  };
  auto stage = [&](int kt, int buf) {
    const size_t k0 = (size_t)kt * 32;
    GLD16(aSrc + k0, &lds[buf][(w * 32) * 32]);
    GLD16(aSrc + k0 + (size_t)16 * lda, &lds[buf][(w * 32 + 16) * 32]);
    GLD16(bSrc + k0, &lds[buf][4096 + (w * 32) * 32]);
    GLD16(bSrc + k0 + (size_t)16 * ldb, &lds[buf][4096 + (w * 32 + 16) * 32]);
  };

  stage(kt_of(0), 0);
  __syncthreads();

  for (int t = 0; t < nt; ++t) {
    const int buf = t & 1;
    if (t + 1 < nt) stage(kt_of(t + 1), buf ^ 1);
    const int sl = gq ^ ((rl >> 1) & 3);
    s16x8 af[4], bfv[4];
#pragma unroll
    for (int fr = 0; fr < 4; ++fr) {
      const int row = wrow + fr * 16 + rl;
      af[fr] = *(const s16x8*)&lds[buf][row * 32 + sl * 8];
    }
#pragma unroll
    for (int fc = 0; fc < 4; ++fc) {
      const int row = wcol + fc * 16 + rl;
      bfv[fc] = *(const s16x8*)&lds[buf][4096 + row * 32 + sl * 8];
    }
#pragma unroll
    for (int fr = 0; fr < 4; ++fr)
#pragma unroll
      for (int fc = 0; fc < 4; ++fc)
        acc[fr][fc] = MFMA16(af[fr], bfv[fc], acc[fr][fc]);

    if constexpr (MODE == 2) {
      if (t == 1 || t == 3) {
        const int wsel = w & 1;
        const bool ad = (t == 1);
#pragma unroll
        for (int fr = 0; fr < 4; ++fr)
#pragma unroll
          for (int r = 0; r < 4; ++r) {
            const int rloc = wrow + fr * 16 + gq * 4 + r;
            const float gl = glds[wsel][0][rloc];
            float s;
            if (ad) { const float gp = glds[wsel][1][rloc]; s = (tq > 0) ? gp / gl : 0.0f; }
            else s = gl;
#pragma unroll
            for (int fc = 0; fc < 4; ++fc) acc[fr][fc][r] *= s;
          }
      }
    }
    __syncthreads();
  }

  if constexpr (MODE == 0) {
#pragma unroll
    for (int fc = 0; fc < 4; ++fc) {
      const int col = bc * 128 + wcol + fc * 16 + rl;
#pragma unroll
      for (int fr = 0; fr < 4; ++fr)
#pragma unroll
        for (int r = 0; r < 4; ++r) {
          const int grow = br * 128 + wrow + fr * 16 + gq * 4 + r;
          const float v = acc[fr][fc][r];
          if (col < 64) {
            ob0[(size_t)grow * 896 + 768 + col] = f2bf(v);
          } else if (col < 128) {
            const float u = v + p0[col - 64];
            const float gv = 0.5f * u * (1.0f + erff(u * 0.70710678118654752f));
            ob0[(size_t)grow * 896 + 832 + (col - 64)] = f2bf(gv);
          } else if (col < 200) {
            const float z = v + p1[col - 128];
            of0[(size_t)grow * 72 + (col - 128)] = 1.0f / (1.0f + expf(-z));
          }
        }
    }
  } else if constexpr (MODE == 1) {
#pragma unroll
    for (int fc = 0; fc < 4; ++fc) {
      const int col = bc * 128 + wcol + fc * 16 + rl;
      const float bb = p0[col], sc = p1[col], sf = p2[col];
#pragma unroll
      for (int fr = 0; fr < 4; ++fr)
#pragma unroll
        for (int r = 0; r < 4; ++r) {
          const int grow = br * 128 + wrow + fr * 16 + gq * 4 + r;
          of0[(size_t)grow * 768 + col] = (acc[fr][fc][r] + bb) * sc + sf;
        }
    }
  } else {
    const int wsel = w & 1;
    const int bq = br >> 3;
    const int n0 = (br & 7) * 128;
    const int cbase = bc * 128 + wcol;
    const int hh = (cbase % 768) / 64;
    float s1v[4], buv[4];
#pragma unroll
    for (int fc = 0; fc < 4; ++fc) {
      const int col = cbase + fc * 16 + rl;
      s1v[fc] = p0[col];
      buv[fc] = (tq > 0) ? p1[col] : 0.0f;
    }
    if (tq < 2) {
      u16* dst = (tq == 0) ? ob0 : ob1;
#pragma unroll
      for (int fr = 0; fr < 4; ++fr)
#pragma unroll
        for (int r = 0; r < 4; ++r) {
          const int rloc = wrow + fr * 16 + gq * 4 + r;
          const float gp = glds[wsel][1][rloc];
          const int n = n0 + rloc;
#pragma unroll
          for (int fc = 0; fc < 4; ++fc) {
            const int d = fc * 16 + rl;
            const float v = acc[fr][fc][r] + s1v[fc] + gp * buv[fc];
            dst[((size_t)(bq * 12 + hh) * 1024 + n) * 64 + d] = f2bf(v);
          }
        }
    } else {
      // v: per-wave LDS transpose -> vT [B,H,64,N]
      u16* L = (u16*)&lds[0][0] + (size_t)w * 4096;
#pragma unroll
      for (int fr = 0; fr < 4; ++fr)
#pragma unroll
        for (int r = 0; r < 4; ++r) {
          const int rloc = wrow + fr * 16 + gq * 4 + r;
          const float gp = glds[wsel][1][rloc];
          const int nloc = fr * 16 + gq * 4 + r;
#pragma unroll
          for (int fc = 0; fc < 4; ++fc) {
            const int d = fc * 16 + rl;
            const float v = acc[fr][fc][r] + s1v[fc] + gp * buv[fc];
            L[(d * 64 + nloc) ^ ((d & 7) << 3)] = f2bf(v);
          }
        }
      const int nw = n0 + wrow;
#pragma unroll
      for (int it = 0; it < 8; ++it) {
        const int d = it * 8 + (l >> 3);
        const int slot = l & 7;
        const s16x8 val = *(const s16x8*)&L[d * 64 + ((slot ^ (d & 7)) << 3)];
        *(s16x8*)(ob2 + ((size_t)(bq * 12 + hh) * 64 + d) * 1024 + nw + slot * 8) = val;
      }
    }
  }
}

// ---------------------------------------------------------------- attention

__global__ __launch_bounds__(256)
void attn_kernel(const u16* __restrict__ Q, const u16* __restrict__ K,
                 const u16* __restrict__ VT, u16* __restrict__ AO) {
  __shared__ __align__(16) u16 kv[2][8192];   // [buf][K 4096 | vT 4096]
  __shared__ __align__(16) u16 plds[4][1024]; // per-wave P 16x64
  const int tid = threadIdx.x, w = tid >> 6, l = tid & 63;
  const int rl = l & 15, gq = l >> 4;
  const int qt = blockIdx.x, bh = blockIdx.y;
  const size_t kb = (size_t)bh * (1024 * 64);

  s16x8 aq0, aq1;
  {
    const u16* qp = Q + kb + (size_t)(qt * 64 + w * 16 + rl) * 64 + gq * 8;
    aq0 = *(const s16x8*)qp;
    aq1 = *(const s16x8*)(qp + 32);
  }

  const int srow = l >> 3;           // 0..7 within 8-row chunk
  const int sslot = (l & 7) ^ srow;  // pre-swizzled source slot
  const u16* kSrc = K + kb + (size_t)(w * 16 + srow) * 64 + sslot * 8;
  const u16* vSrc = VT + kb + (size_t)(w * 16 + srow) * 1024 + sslot * 8;

  auto stage = [&](int t, int buf) {
    const size_t kv0 = (size_t)t * 64;
    GLD16(kSrc + kv0 * 64, &kv[buf][(w * 16) * 64]);
    GLD16(kSrc + kv0 * 64 + 8 * 64, &kv[buf][(w * 16 + 8) * 64]);
    GLD16(vSrc + kv0, &kv[buf][4096 + (w * 16) * 64]);
    GLD16(vSrc + kv0 + 8 * 1024, &kv[buf][4096 + (w * 16 + 8) * 64]);
  };

  f32x4 o[4];
  float mrun[4], lrun[4];
#pragma unroll
  for (int i = 0; i < 4; ++i) { o[i] = zero4(); mrun[i] = -3.0e38f; lrun[i] = 0.f; }
  const float sml = 0.125f * 1.4426950408889634f;

  stage(0, 0);
  __syncthreads();
  for (int t = 0; t < 16; ++t) {
    const int buf = t & 1;
    if (t < 15) stage(t + 1, buf ^ 1);

    f32x4 sa[4];
#pragma unroll
    for (int cf = 0; cf < 4; ++cf) {
      sa[cf] = zero4();
      const int row = cf * 16 + rl;
      const s16x8 bk0 = *(const s16x8*)&kv[buf][row * 64 + ((gq ^ (row & 7)) << 3)];
      const s16x8 bk1 = *(const s16x8*)&kv[buf][row * 64 + (((4 + gq) ^ (row & 7)) << 3)];
      sa[cf] = MFMA16(aq0, bk0, sa[cf]);
      sa[cf] = MFMA16(aq1, bk1, sa[cf]);
    }
#pragma unroll
    for (int cf = 0; cf < 4; ++cf) sa[cf] *= sml;

    float corr[4];
#pragma unroll
    for (int r = 0; r < 4; ++r) {
      float cm = fmaxf(fmaxf(sa[0][r], sa[1][r]), fmaxf(sa[2][r], sa[3][r]));
#pragma unroll
      for (int off = 1; off < 16; off <<= 1) cm = fmaxf(cm, __shfl_xor(cm, off));
      const float mnew = fmaxf(mrun[r], cm);
      corr[r] = exp2f(mrun[r] - mnew);
      mrun[r] = mnew;
      float ps = 0.f;
#pragma unroll
      for (int cf = 0; cf < 4; ++cf) {
        const float p = exp2f(sa[cf][r] - mnew);
        sa[cf][r] = p;
        ps += p;
      }
#pragma unroll
      for (int off = 1; off < 16; off <<= 1) ps += __shfl_xor(ps, off);
      lrun[r] = lrun[r] * corr[r] + ps;
    }
#pragma unroll
    for (int df = 0; df < 4; ++df)
#pragma unroll
      for (int r = 0; r < 4; ++r) o[df][r] *= corr[r];

#pragma unroll
    for (int cf = 0; cf < 4; ++cf)
#pragma unroll
      for (int r = 0; r < 4; ++r) {
        const int prow = gq * 4 + r;
        plds[w][(prow * 64 + cf * 16 + rl) ^ ((prow & 7) << 3)] = f2bf(sa[cf][r]);
      }

    {
      const s16x8 ap0 = *(const s16x8*)&plds[w][rl * 64 + ((gq ^ (rl & 7)) << 3)];
      const s16x8 ap1 = *(const s16x8*)&plds[w][rl * 64 + (((4 + gq) ^ (rl & 7)) << 3)];
#pragma unroll
      for (int df = 0; df < 4; ++df) {
        const int row = df * 16 + rl;
        const s16x8 bv0 = *(const s16x8*)&kv[buf][4096 + row * 64 + ((gq ^ (row & 7)) << 3)];
        const s16x8 bv1 = *(const s16x8*)&kv[buf][4096 + row * 64 + (((4 + gq) ^ (row & 7)) << 3)];
        o[df] = MFMA16(ap0, bv0, o[df]);
        o[df] = MFMA16(ap1, bv1, o[df]);
      }
    }
    __syncthreads();
  }

  const int b = bh / 12, h = bh % 12;
  float inv[4];
#pragma unroll
  for (int r = 0; r < 4; ++r) inv[r] = 1.0f / lrun[r];
#pragma unroll
  for (int df = 0; df < 4; ++df)
#pragma unroll
    for (int r = 0; r < 4; ++r) {
      const int n = qt * 64 + w * 16 + gq * 4 + r;
      const int d = df * 16 + rl;
      AO[((size_t)b * 1024 + n) * 768 + h * 64 + d] = f2bf(o[df][r] * inv[r]);
    }
}

// ---------------------------------------------------------------- launch

extern "C" void kernel_launch(void* const* d_in, const int* in_sizes, int n_in,
                              void* d_out, int out_size, void* d_ws, size_t ws_size,
                              hipStream_t stream) {
  (void)in_sizes; (void)n_in; (void)out_size; (void)ws_size;
  const float* x    = (const float*)d_in[0];
  const float* Wqkv = (const float*)d_in[1];
  const float* s1   = (const float*)d_in[2];
  const float* sh1  = (const float*)d_in[3];
  const float* Wa   = (const float*)d_in[4];
  const float* Wb   = (const float*)d_in[5];
  const float* Wr   = (const float*)d_in[6];
  const float* brt  = (const float*)d_in[7];
  const float* Wdn  = (const float*)d_in[8];
  const float* bdn  = (const float*)d_in[9];
  const float* Wup  = (const float*)d_in[10];
  const float* bup  = (const float*)d_in[11];
  const float* Wp   = (const float*)d_in[12];
  const float* bpj  = (const float*)d_in[13];
  const float* sc2  = (const float*)d_in[14];
  const float* sf2  = (const float*)d_in[15];
  float* out = (float*)d_out;

  char* ws = (char*)d_ws;
  size_t off = 0;
  auto take = [&](size_t bytes) -> void* {
    void* p = ws + off;
    off = (off + bytes + 255) & ~(size_t)255;
    return p;
  };
  u16* Aaug = (u16*)take(8192UL * 896 * 2);
  u16* Baug = (u16*)take(2304UL * 896 * 2);
  u16* Wsm  = (u16*)take(256UL * 768 * 2);
  u16* Wpj  = (u16*)take(768UL * 768 * 2);
  float* gates = (float*)take(8192UL * 72 * 4);
  u16* qb  = (u16*)take(96UL * 1024 * 64 * 2);
  u16* kbf = (u16*)take(96UL * 1024 * 64 * 2);
  u16* vtb = (u16*)take(96UL * 64 * 1024 * 2);
  u16* ao  = (u16*)take(8192UL * 768 * 2);

  prep_x<<<dim3(6144), dim3(256), 0, stream>>>(x, Aaug);
  prep_w<<<dim3(11136), dim3(256), 0, stream>>>(Wqkv, s1, Wb, Wup, Wa, Wdn, Wr, Wp,
                                                Baug, Wsm, Wpj);
  gemm_mfma<0><<<dim3(64, 2), dim3(256), 0, stream>>>(
      Aaug, 896, Wsm, 768, bdn, brt, nullptr, Aaug, nullptr, nullptr, gates, nullptr);
  gemm_mfma<2><<<dim3(64, 18), dim3(256), 0, stream>>>(
      Aaug, 896, Baug, 896, sh1, bup, nullptr, qb, kbf, vtb, nullptr, gates);
  attn_kernel<<<dim3(16, 96), dim3(256), 0, stream>>>(qb, kbf, vtb, ao);
  gemm_mfma<1><<<dim3(64, 6), dim3(256), 0, stream>>>(
      ao, 768, Wpj, 768, bpj, sc2, sf2, nullptr, nullptr, nullptr, out, nullptr);
}

// Round 4
// 207.497 us; speedup vs baseline: 1.1102x; 1.1102x over previous
//
#include <hip/hip_runtime.h>
#include <math.h>

typedef unsigned short u16;
typedef unsigned int u32;
typedef short s16x8 __attribute__((ext_vector_type(8)));
typedef float f32x4 __attribute__((ext_vector_type(4)));
typedef float f32x16 __attribute__((ext_vector_type(16)));
typedef u16 u16x4 __attribute__((ext_vector_type(4)));

#define DEVI __device__ __forceinline__

DEVI u16 f2bf(float f) {
  unsigned u = __builtin_bit_cast(unsigned, f);
  u += 0x7fffu + ((u >> 16) & 1u);
  return (u16)(u >> 16);
}

DEVI u32 pack2bf(float a, float b) {
  return (u32)f2bf(a) | ((u32)f2bf(b) << 16);
}

DEVI f32x4 zero4() { f32x4 z; z[0]=0.f; z[1]=0.f; z[2]=0.f; z[3]=0.f; return z; }

DEVI float xor32_max(float x) { return fmaxf(x, __shfl_xor(x, 32, 64)); }
DEVI float xor32_sum(float x) { return x + __shfl_xor(x, 32, 64); }

#define MFMA16(a,b,c) __builtin_amdgcn_mfma_f32_16x16x32_bf16((a),(b),(c),0,0,0)
#define MFMA32(a,b,c) __builtin_amdgcn_mfma_f32_32x32x16_bf16((a),(b),(c),0,0,0)

#define GLD16(gp, lp) __builtin_amdgcn_global_load_lds( \
  (const __attribute__((address_space(1))) void*)(const void*)(gp), \
  (__attribute__((address_space(3))) void*)(void*)(lp), 16, 0, 0)

// ---------------------------------------------------------------- prep kernels

__global__ __launch_bounds__(256) void prep_x(const float* __restrict__ x,
                                              u16* __restrict__ Aaug) {
  const int i = blockIdx.x * 256 + threadIdx.x;
  if (i >= 8192 * 192) return;
  const int row = i / 192, c4 = (i - row * 192) * 4;
  const float4 v = *(const float4*)(x + (size_t)row * 768 + c4);
  u16x4 o; o[0]=f2bf(v.x); o[1]=f2bf(v.y); o[2]=f2bf(v.z); o[3]=f2bf(v.w);
  *(u16x4*)(Aaug + (size_t)row * 896 + c4) = o;
}

__global__ __launch_bounds__(256) void prep_w(
    const float* __restrict__ Wqkv, const float* __restrict__ s1,
    const float* __restrict__ Wb, const float* __restrict__ Wup,
    const float* __restrict__ Wa, const float* __restrict__ Wdn,
    const float* __restrict__ Wr, const float* __restrict__ Wp,
    u16* __restrict__ Baug, u16* __restrict__ Wsm, u16* __restrict__ Wpj) {
  const int i = blockIdx.x * 256 + threadIdx.x;
  const int N1 = 2304 * 896, N2 = N1 + 256 * 768, N3 = N2 + 768 * 768;
  if (i < N1) {
    const int c = i / 896, kk = i - c * 896;
    float v;
    if (kk < 768)      v = Wqkv[(size_t)c * 768 + kk] * s1[c];
    else if (kk < 832) v = Wb[(size_t)c * 64 + (kk - 768)];
    else               v = Wup[(size_t)c * 64 + (kk - 832)];
    Baug[i] = f2bf(v);
  } else if (i < N2) {
    const int j = i - N1; const int r = j / 768, kk = j - r * 768;
    float v = 0.0f;
    if (r < 64)       v = Wa[(size_t)r * 768 + kk];
    else if (r < 128) v = Wdn[(size_t)(r - 64) * 768 + kk];
    else if (r < 200) v = Wr[(size_t)(r - 128) * 768 + kk];
    Wsm[j] = f2bf(v);
  } else if (i < N3) {
    const int j = i - N2;
    Wpj[j] = f2bf(Wp[j]);
  }
}

// ---------------------------------------------------------------- GEMM kernel

template <int MODE>
__global__ __launch_bounds__(256)
void gemm_mfma(const u16* __restrict__ A, int lda,
               const u16* __restrict__ Bt, int ldb,
               const float* __restrict__ p0, const float* __restrict__ p1,
               const float* __restrict__ p2,
               u16* __restrict__ ob0, u16* __restrict__ ob1, u16* __restrict__ ob2,
               float* __restrict__ of0,
               const float* __restrict__ gates) {
  __shared__ __align__(16) u16 lds[2][8192];
  __shared__ float glds[2][2][128];
  const int tid = threadIdx.x;
  const int w = tid >> 6, l = tid & 63;
  const int rl = l & 15, gq = l >> 4;
  const int wrow = (w >> 1) * 64, wcol = (w & 1) * 64;
  const int br = blockIdx.x, bc = blockIdx.y;
  const int nt = (MODE == 2) ? 28 : 24;

  const int srow = l >> 2;
  const int sslot = (l & 3) ^ ((srow >> 1) & 3);
  const u16* aSrc = A + (size_t)(br * 128 + w * 32 + srow) * lda + sslot * 8;
  const u16* bSrc = Bt + (size_t)(bc * 128 + w * 32 + srow) * ldb + sslot * 8;

  int tq = 0;
  if constexpr (MODE == 2) {
    const int g = bc * 2 + (w & 1);
    tq = g / 12;
    {
      const int gsel = tid >> 7, rr = tid & 127;
      const int gg = bc * 2 + gsel;
      const int tt = gg / 12, hh = gg % 12;
      const int f = hh * 3 + tt;
      const int ridx = (f / 12) * 24 + (f % 12) * 2;
      glds[gsel][0][rr] = gates[(size_t)(br * 128 + rr) * 72 + ridx];
      glds[gsel][1][rr] = gates[(size_t)(br * 128 + rr) * 72 + ridx + 1];
    }
  }

  f32x4 acc[4][4];
#pragma unroll
  for (int i = 0; i < 4; ++i)
#pragma unroll
    for (int j = 0; j < 4; ++j) acc[i][j] = zero4();

  auto kt_of = [&](int t) {
    if constexpr (MODE == 2) return (t < 2) ? 26 + t : ((t < 4) ? 22 + t : t - 4);
    else return t;
  };
  auto stage = [&](int kt, int buf) {
    const size_t k0 = (size_t)kt * 32;
    GLD16(aSrc + k0, &lds[buf][(w * 32) * 32]);
    GLD16(aSrc + k0 + (size_t)16 * lda, &lds[buf][(w * 32 + 16) * 32]);
    GLD16(bSrc + k0, &lds[buf][4096 + (w * 32) * 32]);
    GLD16(bSrc + k0 + (size_t)16 * ldb, &lds[buf][4096 + (w * 32 + 16) * 32]);
  };

  stage(kt_of(0), 0);
  __syncthreads();

  for (int t = 0; t < nt; ++t) {
    const int buf = t & 1;
    if (t + 1 < nt) stage(kt_of(t + 1), buf ^ 1);
    const int sl = gq ^ ((rl >> 1) & 3);
    s16x8 af[4], bfv[4];
#pragma unroll
    for (int fr = 0; fr < 4; ++fr) {
      const int row = wrow + fr * 16 + rl;
      af[fr] = *(const s16x8*)&lds[buf][row * 32 + sl * 8];
    }
#pragma unroll
    for (int fc = 0; fc < 4; ++fc) {
      const int row = wcol + fc * 16 + rl;
      bfv[fc] = *(const s16x8*)&lds[buf][4096 + row * 32 + sl * 8];
    }
#pragma unroll
    for (int fr = 0; fr < 4; ++fr)
#pragma unroll
      for (int fc = 0; fc < 4; ++fc)
        acc[fr][fc] = MFMA16(af[fr], bfv[fc], acc[fr][fc]);

    if constexpr (MODE == 2) {
      if (t == 1 || t == 3) {
        const int wsel = w & 1;
        const bool ad = (t == 1);
#pragma unroll
        for (int fr = 0; fr < 4; ++fr)
#pragma unroll
          for (int r = 0; r < 4; ++r) {
            const int rloc = wrow + fr * 16 + gq * 4 + r;
            const float gl = glds[wsel][0][rloc];
            float s;
            if (ad) { const float gp = glds[wsel][1][rloc]; s = (tq > 0) ? gp / gl : 0.0f; }
            else s = gl;
#pragma unroll
            for (int fc = 0; fc < 4; ++fc) acc[fr][fc][r] *= s;
          }
      }
    }
    __syncthreads();
  }

  if constexpr (MODE == 0) {
#pragma unroll
    for (int fc = 0; fc < 4; ++fc) {
      const int col = bc * 128 + wcol + fc * 16 + rl;
#pragma unroll
      for (int fr = 0; fr < 4; ++fr)
#pragma unroll
        for (int r = 0; r < 4; ++r) {
          const int grow = br * 128 + wrow + fr * 16 + gq * 4 + r;
          const float v = acc[fr][fc][r];
          if (col < 64) {
            ob0[(size_t)grow * 896 + 768 + col] = f2bf(v);
          } else if (col < 128) {
            const float u = v + p0[col - 64];
            const float gv = 0.5f * u * (1.0f + erff(u * 0.70710678118654752f));
            ob0[(size_t)grow * 896 + 832 + (col - 64)] = f2bf(gv);
          } else if (col < 200) {
            const float z = v + p1[col - 128];
            of0[(size_t)grow * 72 + (col - 128)] = 1.0f / (1.0f + expf(-z));
          }
        }
    }
  } else if constexpr (MODE == 1) {
#pragma unroll
    for (int fc = 0; fc < 4; ++fc) {
      const int col = bc * 128 + wcol + fc * 16 + rl;
      const float bb = p0[col], sc = p1[col], sf = p2[col];
#pragma unroll
      for (int fr = 0; fr < 4; ++fr)
#pragma unroll
        for (int r = 0; r < 4; ++r) {
          const int grow = br * 128 + wrow + fr * 16 + gq * 4 + r;
          of0[(size_t)grow * 768 + col] = (acc[fr][fc][r] + bb) * sc + sf;
        }
    }
  } else {
    const int wsel = w & 1;
    const int bq = br >> 3;
    const int n0 = (br & 7) * 128;
    const int cbase = bc * 128 + wcol;
    const int hh = (cbase % 768) / 64;
    float s1v[4], buv[4];
#pragma unroll
    for (int fc = 0; fc < 4; ++fc) {
      const int col = cbase + fc * 16 + rl;
      s1v[fc] = p0[col];
      buv[fc] = (tq > 0) ? p1[col] : 0.0f;
    }
    if (tq < 2) {
      u16* dst = (tq == 0) ? ob0 : ob1;
      const float osc = (tq == 0) ? 0.125f : 1.0f;  // fold attn scale into q (exact)
#pragma unroll
      for (int fr = 0; fr < 4; ++fr)
#pragma unroll
        for (int r = 0; r < 4; ++r) {
          const int rloc = wrow + fr * 16 + gq * 4 + r;
          const float gp = glds[wsel][1][rloc];
          const int n = n0 + rloc;
#pragma unroll
          for (int fc = 0; fc < 4; ++fc) {
            const int d = fc * 16 + rl;
            const float v = (acc[fr][fc][r] + s1v[fc] + gp * buv[fc]) * osc;
            dst[((size_t)(bq * 12 + hh) * 1024 + n) * 64 + d] = f2bf(v);
          }
        }
    } else {
      u16* L = (u16*)&lds[0][0] + (size_t)w * 4096;
#pragma unroll
      for (int fr = 0; fr < 4; ++fr)
#pragma unroll
        for (int r = 0; r < 4; ++r) {
          const int rloc = wrow + fr * 16 + gq * 4 + r;
          const float gp = glds[wsel][1][rloc];
          const int nloc = fr * 16 + gq * 4 + r;
#pragma unroll
          for (int fc = 0; fc < 4; ++fc) {
            const int d = fc * 16 + rl;
            const float v = acc[fr][fc][r] + s1v[fc] + gp * buv[fc];
            L[(d * 64 + nloc) ^ ((d & 7) << 3)] = f2bf(v);
          }
        }
      const int nw = n0 + wrow;
#pragma unroll
      for (int it = 0; it < 8; ++it) {
        const int d = it * 8 + (l >> 3);
        const int slot = l & 7;
        const s16x8 val = *(const s16x8*)&L[d * 64 + ((slot ^ (d & 7)) << 3)];
        *(s16x8*)(ob2 + ((size_t)(bq * 12 + hh) * 64 + d) * 1024 + nw + slot * 8) = val;
      }
    }
  }
}

// ---------------------------------------------------------------- attention
// Swapped-QK^T 32x32 structure; P repack via proven f2bf + __shfl_xor(32).

__global__ __launch_bounds__(256)
void attn2_kernel(const u16* __restrict__ Q, const u16* __restrict__ K,
                  const u16* __restrict__ VT, u16* __restrict__ AO) {
  __shared__ __align__(16) u16 kv[2][8192];  // [buf][ K 64x64 | VT 64x64 ]
  const int tid = threadIdx.x, w = tid >> 6, l = tid & 63;
  const int l31 = l & 31, hi = l >> 5;
  const int bh = blockIdx.x % 96, qt = blockIdx.x / 96;
  const size_t kb = (size_t)bh * (1024 * 64);
  const float LOG2E = 1.4426950408889634f;
  const float THR = 5.545177f;               // = 8/log2(e), raw-S units

  // Q fragments (B-operand): lane holds Q[q0+l31][ks*16 + hi*8 + j]
  const int q0 = qt * 128 + w * 32;
  s16x8 qf[4];
  {
    const u16* qp = Q + kb + (size_t)(q0 + l31) * 64 + hi * 8;
#pragma unroll
    for (int ks = 0; ks < 4; ++ks) qf[ks] = *(const s16x8*)(qp + ks * 16);
  }

  // staging (pre-swizzled source, linear LDS dest)
  const int srow = l >> 3;
  const int sslot = (l & 7) ^ srow;
  const u16* kSrc = K + kb + (size_t)(w * 16 + srow) * 64 + sslot * 8;
  const u16* vSrc = VT + kb + (size_t)(w * 16 + srow) * 1024 + sslot * 8;
  auto stage = [&](int t, int buf) {
    const int kv0 = t * 64;
    GLD16(kSrc + (size_t)kv0 * 64, &kv[buf][(w * 16) * 64]);
    GLD16(kSrc + (size_t)kv0 * 64 + 8 * 64, &kv[buf][(w * 16 + 8) * 64]);
    GLD16(vSrc + kv0, &kv[buf][4096 + (w * 16) * 64]);
    GLD16(vSrc + kv0 + 8 * 1024, &kv[buf][4096 + (w * 16 + 8) * 64]);
  };

  f32x16 o0, o1;
#pragma unroll
  for (int r = 0; r < 16; ++r) { o0[r] = 0.f; o1[r] = 0.f; }
  float m = -1.0e30f, lsum = 0.f;

  const int swz = l31 & 7;

  stage(0, 0);
  __syncthreads();

  for (int t = 0; t < 16; ++t) {
    const int buf = t & 1;
    if (t < 15) stage(t + 1, buf ^ 1);

    // ---- QK^T: S^T[kv][q]; lane q-col = l31; kv(r,hi) = (r&3)+8*(r>>2)+4*hi
    f32x16 sA, sB;
#pragma unroll
    for (int r = 0; r < 16; ++r) { sA[r] = 0.f; sB[r] = 0.f; }
#pragma unroll
    for (int ks = 0; ks < 4; ++ks) {
      const int slot = (ks * 2 + hi) ^ swz;
      const s16x8 k0 = *(const s16x8*)&kv[buf][l31 * 64 + slot * 8];
      const s16x8 k1 = *(const s16x8*)&kv[buf][(32 + l31) * 64 + slot * 8];
      sA = MFMA32(k0, qf[ks], sA);
      sB = MFMA32(k1, qf[ks], sB);
    }

    // ---- online softmax (per-lane: one q = l31)
    float pm = sA[0];
#pragma unroll
    for (int r = 1; r < 16; ++r) pm = fmaxf(pm, sA[r]);
#pragma unroll
    for (int r = 0; r < 16; ++r) pm = fmaxf(pm, sB[r]);
    pm = xor32_max(pm);

    const bool need = pm > m + THR;
    if (__any(need)) {
      const float mnew = need ? pm : m;
      const float corr = __builtin_amdgcn_exp2f((m - mnew) * LOG2E);
      m = mnew;
      lsum *= corr;
#pragma unroll
      for (int r = 0; r < 16; ++r) {
        const int qrow = (r & 3) + 8 * (r >> 2) + 4 * hi;
        const float cr = __shfl(corr, qrow, 64);
        o0[r] *= cr; o1[r] *= cr;
      }
    }

    const float mL = m * LOG2E;
    float ps = 0.f;
#pragma unroll
    for (int r = 0; r < 16; ++r) {
      const float p = __builtin_amdgcn_exp2f(__builtin_fmaf(sA[r], LOG2E, -mL));
      sA[r] = p; ps += p;
    }
#pragma unroll
    for (int r = 0; r < 16; ++r) {
      const float p = __builtin_amdgcn_exp2f(__builtin_fmaf(sB[r], LOG2E, -mL));
      sB[r] = p; ps += p;
    }
    lsum += xor32_sum(ps);

    // ---- P -> bf16 A-fragments via pack + shfl_xor(32) + per-half select.
    // Lane (l31,hi) must supply P[q=l31][kv = 16s + 8*hi + j], j=0..7.
    // Own regs hold kv = (r&3)+8*(r>>2)+4*hi; partner (hi^1) holds the rest.
    s16x8 pf[4];
#pragma unroll
    for (int s = 0; s < 4; ++s) {
      const f32x16 P = (s < 2) ? sA : sB;
      const int b = 8 * (s & 1);
      const u32 A0 = pack2bf(P[b + 0], P[b + 1]);  // kv 16s+4hi+{0,1}
      const u32 A1 = pack2bf(P[b + 2], P[b + 3]);  // kv 16s+4hi+{2,3}
      const u32 A2 = pack2bf(P[b + 4], P[b + 5]);  // kv 16s+8+4hi+{0,1}
      const u32 A3 = pack2bf(P[b + 6], P[b + 7]);  // kv 16s+8+4hi+{2,3}
      const u32 B0 = (u32)__shfl_xor((int)A0, 32, 64);
      const u32 B1 = (u32)__shfl_xor((int)A1, 32, 64);
      const u32 B2 = (u32)__shfl_xor((int)A2, 32, 64);
      const u32 B3 = (u32)__shfl_xor((int)A3, 32, 64);
      union { u32 u[4]; s16x8 v; } pk;
      pk.u[0] = hi ? B2 : A0;   // kv 16s+8hi+{0,1}
      pk.u[1] = hi ? B3 : A1;   // kv 16s+8hi+{2,3}
      pk.u[2] = hi ? A2 : B0;   // kv 16s+8hi+{4,5}
      pk.u[3] = hi ? A3 : B1;   // kv 16s+8hi+{6,7}
      pf[s] = pk.v;
    }

    // ---- PV: O[q][d] += P V, d halves
#pragma unroll
    for (int s = 0; s < 4; ++s) {
      const int slot = (s * 2 + hi) ^ swz;
      const s16x8 v0 = *(const s16x8*)&kv[buf][4096 + l31 * 64 + slot * 8];
      const s16x8 v1 = *(const s16x8*)&kv[buf][4096 + (32 + l31) * 64 + slot * 8];
      o0 = MFMA32(pf[s], v0, o0);
      o1 = MFMA32(pf[s], v1, o1);
    }
    __syncthreads();
  }

  // ---- epilogue
  const float invl = 1.0f / lsum;
  const int bq = bh / 12, h = bh % 12;
#pragma unroll
  for (int r = 0; r < 16; ++r) {
    const int qrow = (r & 3) + 8 * (r >> 2) + 4 * hi;
    const float ir = __shfl(invl, qrow, 64);
    const int n = q0 + qrow;
    u16* dst = AO + ((size_t)bq * 1024 + n) * 768 + h * 64 + l31;
    dst[0]  = f2bf(o0[r] * ir);
    dst[32] = f2bf(o1[r] * ir);
  }
}

// ---------------------------------------------------------------- launch

extern "C" void kernel_launch(void* const* d_in, const int* in_sizes, int n_in,
                              void* d_out, int out_size, void* d_ws, size_t ws_size,
                              hipStream_t stream) {
  (void)in_sizes; (void)n_in; (void)out_size; (void)ws_size;
  const float* x    = (const float*)d_in[0];
  const float* Wqkv = (const float*)d_in[1];
  const float* s1   = (const float*)d_in[2];
  const float* sh1  = (const float*)d_in[3];
  const float* Wa   = (const float*)d_in[4];
  const float* Wb   = (const float*)d_in[5];
  const float* Wr   = (const float*)d_in[6];
  const float* brt  = (const float*)d_in[7];
  const float* Wdn  = (const float*)d_in[8];
  const float* bdn  = (const float*)d_in[9];
  const float* Wup  = (const float*)d_in[10];
  const float* bup  = (const float*)d_in[11];
  const float* Wp   = (const float*)d_in[12];
  const float* bpj  = (const float*)d_in[13];
  const float* sc2  = (const float*)d_in[14];
  const float* sf2  = (const float*)d_in[15];
  float* out = (float*)d_out;

  char* ws = (char*)d_ws;
  size_t off = 0;
  auto take = [&](size_t bytes) -> void* {
    void* p = ws + off;
    off = (off + bytes + 255) & ~(size_t)255;
    return p;
  };
  u16* Aaug = (u16*)take(8192UL * 896 * 2);
  u16* Baug = (u16*)take(2304UL * 896 * 2);
  u16* Wsm  = (u16*)take(256UL * 768 * 2);
  u16* Wpj  = (u16*)take(768UL * 768 * 2);
  float* gates = (float*)take(8192UL * 72 * 4);
  u16* qb  = (u16*)take(96UL * 1024 * 64 * 2);
  u16* kbf = (u16*)take(96UL * 1024 * 64 * 2);
  u16* vtb = (u16*)take(96UL * 64 * 1024 * 2);
  u16* ao  = (u16*)take(8192UL * 768 * 2);

  prep_x<<<dim3(6144), dim3(256), 0, stream>>>(x, Aaug);
  prep_w<<<dim3(11136), dim3(256), 0, stream>>>(Wqkv, s1, Wb, Wup, Wa, Wdn, Wr, Wp,
                                                Baug, Wsm, Wpj);
  gemm_mfma<0><<<dim3(64, 2), dim3(256), 0, stream>>>(
      Aaug, 896, Wsm, 768, bdn, brt, nullptr, Aaug, nullptr, nullptr, gates, nullptr);
  gemm_mfma<2><<<dim3(64, 18), dim3(256), 0, stream>>>(
      Aaug, 896, Baug, 896, sh1, bup, nullptr, qb, kbf, vtb, nullptr, gates);
  attn2_kernel<<<dim3(768), dim3(256), 0, stream>>>(qb, kbf, vtb, ao);
  gemm_mfma<1><<<dim3(64, 6), dim3(256), 0, stream>>>(
      ao, 768, Wpj, 768, bpj, sc2, sf2, nullptr, nullptr, nullptr, out, nullptr);
}

// Round 5
// 202.889 us; speedup vs baseline: 1.1354x; 1.0227x over previous
//
#include <hip/hip_runtime.h>
#include <math.h>

typedef unsigned short u16;
typedef unsigned int u32;
typedef short s16x8 __attribute__((ext_vector_type(8)));
typedef float f32x4 __attribute__((ext_vector_type(4)));
typedef float f32x16 __attribute__((ext_vector_type(16)));
typedef u16 u16x4 __attribute__((ext_vector_type(4)));

#define DEVI __device__ __forceinline__

DEVI u16 f2bf(float f) {
  unsigned u = __builtin_bit_cast(unsigned, f);
  u += 0x7fffu + ((u >> 16) & 1u);
  return (u16)(u >> 16);
}

// pack two f32 -> 2x bf16 with round-half-up (+0x8000) via one v_perm_b32
DEVI u32 pkbf_hu(float a, float b) {
  const u32 ua = __builtin_bit_cast(u32, a) + 0x8000u;
  const u32 ub = __builtin_bit_cast(u32, b) + 0x8000u;
  return __builtin_amdgcn_perm(ub, ua, 0x07060302u);  // {ub[3],ub[2],ua[3],ua[2]}
}

DEVI f32x4 zero4() { f32x4 z; z[0]=0.f; z[1]=0.f; z[2]=0.f; z[3]=0.f; return z; }

DEVI float xor32_max(float x) { return fmaxf(x, __shfl_xor(x, 32, 64)); }
DEVI float xor32_sum(float x) { return x + __shfl_xor(x, 32, 64); }

#define MFMA16(a,b,c) __builtin_amdgcn_mfma_f32_16x16x32_bf16((a),(b),(c),0,0,0)
#define MFMA32(a,b,c) __builtin_amdgcn_mfma_f32_32x32x16_bf16((a),(b),(c),0,0,0)

#define GLD16(gp, lp) __builtin_amdgcn_global_load_lds( \
  (const __attribute__((address_space(1))) void*)(const void*)(gp), \
  (__attribute__((address_space(3))) void*)(void*)(lp), 16, 0, 0)

// ---------------------------------------------------------------- prep kernels

__global__ __launch_bounds__(256) void prep_x(const float* __restrict__ x,
                                              u16* __restrict__ Aaug) {
  const int i = blockIdx.x * 256 + threadIdx.x;
  if (i >= 8192 * 192) return;
  const int row = i / 192, c4 = (i - row * 192) * 4;
  const float4 v = *(const float4*)(x + (size_t)row * 768 + c4);
  u16x4 o; o[0]=f2bf(v.x); o[1]=f2bf(v.y); o[2]=f2bf(v.z); o[3]=f2bf(v.w);
  *(u16x4*)(Aaug + (size_t)row * 896 + c4) = o;
}

__global__ __launch_bounds__(256) void prep_w(
    const float* __restrict__ Wqkv, const float* __restrict__ s1,
    const float* __restrict__ Wb, const float* __restrict__ Wup,
    const float* __restrict__ Wa, const float* __restrict__ Wdn,
    const float* __restrict__ Wr, const float* __restrict__ Wp,
    u16* __restrict__ Baug, u16* __restrict__ Wsm, u16* __restrict__ Wpj) {
  const int i = blockIdx.x * 256 + threadIdx.x;
  const int N1 = 2304 * 896, N2 = N1 + 256 * 768, N3 = N2 + 768 * 768;
  if (i < N1) {
    const int c = i / 896, kk = i - c * 896;
    float v;
    if (kk < 768)      v = Wqkv[(size_t)c * 768 + kk] * s1[c];
    else if (kk < 832) v = Wb[(size_t)c * 64 + (kk - 768)];
    else               v = Wup[(size_t)c * 64 + (kk - 832)];
    Baug[i] = f2bf(v);
  } else if (i < N2) {
    const int j = i - N1; const int r = j / 768, kk = j - r * 768;
    float v = 0.0f;
    if (r < 64)       v = Wa[(size_t)r * 768 + kk];
    else if (r < 128) v = Wdn[(size_t)(r - 64) * 768 + kk];
    else if (r < 200) v = Wr[(size_t)(r - 128) * 768 + kk];
    Wsm[j] = f2bf(v);
  } else if (i < N3) {
    const int j = i - N2;
    Wpj[j] = f2bf(Wp[j]);
  }
}

// ---------------------------------------------------------------- GEMM kernel

template <int MODE>
__global__ __launch_bounds__(256)
void gemm_mfma(const u16* __restrict__ A, int lda,
               const u16* __restrict__ Bt, int ldb,
               const float* __restrict__ p0, const float* __restrict__ p1,
               const float* __restrict__ p2,
               u16* __restrict__ ob0, u16* __restrict__ ob1, u16* __restrict__ ob2,
               float* __restrict__ of0,
               const float* __restrict__ gates) {
  __shared__ __align__(16) u16 lds[2][8192];
  __shared__ float glds[2][2][128];
  const int tid = threadIdx.x;
  const int w = tid >> 6, l = tid & 63;
  const int rl = l & 15, gq = l >> 4;
  const int wrow = (w >> 1) * 64, wcol = (w & 1) * 64;
  const int br = blockIdx.x, bc = blockIdx.y;
  const int nt = (MODE == 2) ? 28 : 24;

  const int srow = l >> 2;
  const int sslot = (l & 3) ^ ((srow >> 1) & 3);
  const u16* aSrc = A + (size_t)(br * 128 + w * 32 + srow) * lda + sslot * 8;
  const u16* bSrc = Bt + (size_t)(bc * 128 + w * 32 + srow) * ldb + sslot * 8;

  int tq = 0;
  if constexpr (MODE == 2) {
    const int g = bc * 2 + (w & 1);
    tq = g / 12;
    {
      const int gsel = tid >> 7, rr = tid & 127;
      const int gg = bc * 2 + gsel;
      const int tt = gg / 12, hh = gg % 12;
      const int f = hh * 3 + tt;
      const int ridx = (f / 12) * 24 + (f % 12) * 2;
      glds[gsel][0][rr] = gates[(size_t)(br * 128 + rr) * 72 + ridx];
      glds[gsel][1][rr] = gates[(size_t)(br * 128 + rr) * 72 + ridx + 1];
    }
  }

  f32x4 acc[4][4];
#pragma unroll
  for (int i = 0; i < 4; ++i)
#pragma unroll
    for (int j = 0; j < 4; ++j) acc[i][j] = zero4();

  auto kt_of = [&](int t) {
    if constexpr (MODE == 2) return (t < 2) ? 26 + t : ((t < 4) ? 22 + t : t - 4);
    else return t;
  };
  auto stage = [&](int kt, int buf) {
    const size_t k0 = (size_t)kt * 32;
    GLD16(aSrc + k0, &lds[buf][(w * 32) * 32]);
    GLD16(aSrc + k0 + (size_t)16 * lda, &lds[buf][(w * 32 + 16) * 32]);
    GLD16(bSrc + k0, &lds[buf][4096 + (w * 32) * 32]);
    GLD16(bSrc + k0 + (size_t)16 * ldb, &lds[buf][4096 + (w * 32 + 16) * 32]);
  };

  stage(kt_of(0), 0);
  __syncthreads();

  for (int t = 0; t < nt; ++t) {
    const int buf = t & 1;
    if (t + 1 < nt) stage(kt_of(t + 1), buf ^ 1);
    const int sl = gq ^ ((rl >> 1) & 3);
    s16x8 af[4], bfv[4];
#pragma unroll
    for (int fr = 0; fr < 4; ++fr) {
      const int row = wrow + fr * 16 + rl;
      af[fr] = *(const s16x8*)&lds[buf][row * 32 + sl * 8];
    }
#pragma unroll
    for (int fc = 0; fc < 4; ++fc) {
      const int row = wcol + fc * 16 + rl;
      bfv[fc] = *(const s16x8*)&lds[buf][4096 + row * 32 + sl * 8];
    }
#pragma unroll
    for (int fr = 0; fr < 4; ++fr)
#pragma unroll
      for (int fc = 0; fc < 4; ++fc)
        acc[fr][fc] = MFMA16(af[fr], bfv[fc], acc[fr][fc]);

    if constexpr (MODE == 2) {
      if (t == 1 || t == 3) {
        const int wsel = w & 1;
        const bool ad = (t == 1);
#pragma unroll
        for (int fr = 0; fr < 4; ++fr)
#pragma unroll
          for (int r = 0; r < 4; ++r) {
            const int rloc = wrow + fr * 16 + gq * 4 + r;
            const float gl = glds[wsel][0][rloc];
            float s;
            if (ad) { const float gp = glds[wsel][1][rloc]; s = (tq > 0) ? gp / gl : 0.0f; }
            else s = gl;
#pragma unroll
            for (int fc = 0; fc < 4; ++fc) acc[fr][fc][r] *= s;
          }
      }
    }
    __syncthreads();
  }

  if constexpr (MODE == 0) {
#pragma unroll
    for (int fc = 0; fc < 4; ++fc) {
      const int col = bc * 128 + wcol + fc * 16 + rl;
#pragma unroll
      for (int fr = 0; fr < 4; ++fr)
#pragma unroll
        for (int r = 0; r < 4; ++r) {
          const int grow = br * 128 + wrow + fr * 16 + gq * 4 + r;
          const float v = acc[fr][fc][r];
          if (col < 64) {
            ob0[(size_t)grow * 896 + 768 + col] = f2bf(v);
          } else if (col < 128) {
            const float u = v + p0[col - 64];
            const float gv = 0.5f * u * (1.0f + erff(u * 0.70710678118654752f));
            ob0[(size_t)grow * 896 + 832 + (col - 64)] = f2bf(gv);
          } else if (col < 200) {
            const float z = v + p1[col - 128];
            of0[(size_t)grow * 72 + (col - 128)] = 1.0f / (1.0f + expf(-z));
          }
        }
    }
  } else if constexpr (MODE == 1) {
#pragma unroll
    for (int fc = 0; fc < 4; ++fc) {
      const int col = bc * 128 + wcol + fc * 16 + rl;
      const float bb = p0[col], sc = p1[col], sf = p2[col];
#pragma unroll
      for (int fr = 0; fr < 4; ++fr)
#pragma unroll
        for (int r = 0; r < 4; ++r) {
          const int grow = br * 128 + wrow + fr * 16 + gq * 4 + r;
          of0[(size_t)grow * 768 + col] = (acc[fr][fc][r] + bb) * sc + sf;
        }
    }
  } else {
    const int wsel = w & 1;
    const int bq = br >> 3;
    const int n0 = (br & 7) * 128;
    const int cbase = bc * 128 + wcol;
    const int hh = (cbase % 768) / 64;
    float s1v[4], buv[4];
#pragma unroll
    for (int fc = 0; fc < 4; ++fc) {
      const int col = cbase + fc * 16 + rl;
      s1v[fc] = p0[col];
      buv[fc] = (tq > 0) ? p1[col] : 0.0f;
    }
    if (tq < 2) {
      // q/k: LDS-staged epilogue -> coalesced 16B stores
      u16* L = (u16*)&lds[0][0] + (size_t)w * 4096;
      u16* dst = (tq == 0) ? ob0 : ob1;
      const float osc = (tq == 0) ? 0.125f : 1.0f;  // fold attn scale into q
#pragma unroll
      for (int fr = 0; fr < 4; ++fr)
#pragma unroll
        for (int r = 0; r < 4; ++r) {
          const int nloc = fr * 16 + gq * 4 + r;
          const float gp = glds[wsel][1][wrow + nloc];
#pragma unroll
          for (int fc = 0; fc < 4; ++fc) {
            const int d = fc * 16 + rl;
            const float v = (acc[fr][fc][r] + s1v[fc] + gp * buv[fc]) * osc;
            L[nloc * 64 + (d ^ (gq << 4))] = f2bf(v);
          }
        }
      const size_t rowbase = (size_t)(bq * 12 + hh) * 1024 + n0 + wrow;
#pragma unroll
      for (int it = 0; it < 8; ++it) {
        const int nloc = it * 8 + (l >> 3);
        const int sl8 = l & 7;
        const s16x8 val =
            *(const s16x8*)&L[nloc * 64 + ((sl8 * 8) ^ (((nloc >> 2) & 3) << 4))];
        *(s16x8*)(dst + (rowbase + nloc) * 64 + sl8 * 8) = val;
      }
    } else {
      u16* L = (u16*)&lds[0][0] + (size_t)w * 4096;
#pragma unroll
      for (int fr = 0; fr < 4; ++fr)
#pragma unroll
        for (int r = 0; r < 4; ++r) {
          const int rloc = wrow + fr * 16 + gq * 4 + r;
          const float gp = glds[wsel][1][rloc];
          const int nloc = fr * 16 + gq * 4 + r;
#pragma unroll
          for (int fc = 0; fc < 4; ++fc) {
            const int d = fc * 16 + rl;
            const float v = acc[fr][fc][r] + s1v[fc] + gp * buv[fc];
            L[(d * 64 + nloc) ^ ((d & 7) << 3)] = f2bf(v);
          }
        }
      const int nw = n0 + wrow;
#pragma unroll
      for (int it = 0; it < 8; ++it) {
        const int d = it * 8 + (l >> 3);
        const int slot = l & 7;
        const s16x8 val = *(const s16x8*)&L[d * 64 + ((slot ^ (d & 7)) << 3)];
        *(s16x8*)(ob2 + ((size_t)(bq * 12 + hh) * 64 + d) * 1024 + nw + slot * 8) = val;
      }
    }
  }
}

// ---------------------------------------------------------------- attention
// Swapped-QK^T 32x32; P repack via perm-pack + shfl_xor(32); counted-vmcnt
// pipeline (raw s_barrier, prefetch loads stay in flight across barrier).

__global__ __launch_bounds__(256)
void attn2_kernel(const u16* __restrict__ Q, const u16* __restrict__ K,
                  const u16* __restrict__ VT, u16* __restrict__ AO) {
  __shared__ __align__(16) u16 kv[2][8192];  // [buf][ K 64x64 | VT 64x64 ]
  const int tid = threadIdx.x, w = tid >> 6, l = tid & 63;
  const int l31 = l & 31, hi = l >> 5;
  const int bh = blockIdx.x % 96, qt = blockIdx.x / 96;
  const size_t kb = (size_t)bh * (1024 * 64);
  const float LOG2E = 1.4426950408889634f;
  const float THR = 5.545177f;               // = 8/log2(e), raw-S units

  const int q0 = qt * 128 + w * 32;
  s16x8 qf[4];
  {
    const u16* qp = Q + kb + (size_t)(q0 + l31) * 64 + hi * 8;
#pragma unroll
    for (int ks = 0; ks < 4; ++ks) qf[ks] = *(const s16x8*)(qp + ks * 16);
  }

  const int srow = l >> 3;
  const int sslot = (l & 7) ^ srow;
  const u16* kSrc = K + kb + (size_t)(w * 16 + srow) * 64 + sslot * 8;
  const u16* vSrc = VT + kb + (size_t)(w * 16 + srow) * 1024 + sslot * 8;
  auto stage = [&](int t, int buf) {
    const int kv0 = t * 64;
    GLD16(kSrc + (size_t)kv0 * 64, &kv[buf][(w * 16) * 64]);
    GLD16(kSrc + (size_t)kv0 * 64 + 8 * 64, &kv[buf][(w * 16 + 8) * 64]);
    GLD16(vSrc + kv0, &kv[buf][4096 + (w * 16) * 64]);
    GLD16(vSrc + kv0 + 8 * 1024, &kv[buf][4096 + (w * 16 + 8) * 64]);
  };

  f32x16 o0, o1;
#pragma unroll
  for (int r = 0; r < 16; ++r) { o0[r] = 0.f; o1[r] = 0.f; }
  float m = -1.0e30f, lsum = 0.f;

  const int swz = l31 & 7;

  stage(0, 0);

  for (int t = 0; t < 16; ++t) {
    const int buf = t & 1;
    if (t < 15) {
      stage(t + 1, buf ^ 1);                         // prefetch (stays in flight)
      asm volatile("s_waitcnt vmcnt(4)" ::: "memory");  // only tile t drained
    } else {
      asm volatile("s_waitcnt vmcnt(0)" ::: "memory");
    }
    __builtin_amdgcn_s_barrier();

    // ---- QK^T: S^T[kv][q]; lane q-col = l31; kv(r,hi) = (r&3)+8*(r>>2)+4*hi
    f32x16 sA, sB;
#pragma unroll
    for (int r = 0; r < 16; ++r) { sA[r] = 0.f; sB[r] = 0.f; }
#pragma unroll
    for (int ks = 0; ks < 4; ++ks) {
      const int slot = (ks * 2 + hi) ^ swz;
      const s16x8 k0 = *(const s16x8*)&kv[buf][l31 * 64 + slot * 8];
      const s16x8 k1 = *(const s16x8*)&kv[buf][(32 + l31) * 64 + slot * 8];
      sA = MFMA32(k0, qf[ks], sA);
      sB = MFMA32(k1, qf[ks], sB);
    }

    // ---- online softmax (per-lane: one q = l31)
    float pm = sA[0];
#pragma unroll
    for (int r = 1; r < 16; ++r) pm = fmaxf(pm, sA[r]);
#pragma unroll
    for (int r = 0; r < 16; ++r) pm = fmaxf(pm, sB[r]);
    pm = xor32_max(pm);

    const bool need = pm > m + THR;
    if (__any(need)) {
      const float mnew = need ? pm : m;
      const float corr = __builtin_amdgcn_exp2f((m - mnew) * LOG2E);
      m = mnew;
      lsum *= corr;
#pragma unroll
      for (int r = 0; r < 16; ++r) {
        const int qrow = (r & 3) + 8 * (r >> 2) + 4 * hi;
        const float cr = __shfl(corr, qrow, 64);
        o0[r] *= cr; o1[r] *= cr;
      }
    }

    const float mL = m * LOG2E;
    float ps = 0.f;
#pragma unroll
    for (int r = 0; r < 16; ++r) {
      const float p = __builtin_amdgcn_exp2f(__builtin_fmaf(sA[r], LOG2E, -mL));
      sA[r] = p; ps += p;
    }
#pragma unroll
    for (int r = 0; r < 16; ++r) {
      const float p = __builtin_amdgcn_exp2f(__builtin_fmaf(sB[r], LOG2E, -mL));
      sB[r] = p; ps += p;
    }
    lsum += xor32_sum(ps);

    // ---- P -> bf16 A-fragments via perm-pack + shfl_xor(32) + per-half select
    s16x8 pf[4];
#pragma unroll
    for (int s = 0; s < 4; ++s) {
      const f32x16 P = (s < 2) ? sA : sB;
      const int b = 8 * (s & 1);
      const u32 A0 = pkbf_hu(P[b + 0], P[b + 1]);  // kv 16s+4hi+{0,1}
      const u32 A1 = pkbf_hu(P[b + 2], P[b + 3]);  // kv 16s+4hi+{2,3}
      const u32 A2 = pkbf_hu(P[b + 4], P[b + 5]);  // kv 16s+8+4hi+{0,1}
      const u32 A3 = pkbf_hu(P[b + 6], P[b + 7]);  // kv 16s+8+4hi+{2,3}
      const u32 B0 = (u32)__shfl_xor((int)A0, 32, 64);
      const u32 B1 = (u32)__shfl_xor((int)A1, 32, 64);
      const u32 B2 = (u32)__shfl_xor((int)A2, 32, 64);
      const u32 B3 = (u32)__shfl_xor((int)A3, 32, 64);
      union { u32 u[4]; s16x8 v; } pk;
      pk.u[0] = hi ? B2 : A0;
      pk.u[1] = hi ? B3 : A1;
      pk.u[2] = hi ? A2 : B0;
      pk.u[3] = hi ? A3 : B1;
      pf[s] = pk.v;
    }

    // ---- PV
#pragma unroll
    for (int s = 0; s < 4; ++s) {
      const int slot = (s * 2 + hi) ^ swz;
      const s16x8 v0 = *(const s16x8*)&kv[buf][4096 + l31 * 64 + slot * 8];
      const s16x8 v1 = *(const s16x8*)&kv[buf][4096 + (32 + l31) * 64 + slot * 8];
      o0 = MFMA32(pf[s], v0, o0);
      o1 = MFMA32(pf[s], v1, o1);
    }
    __builtin_amdgcn_s_barrier();   // all waves done reading kv[buf]
  }

  // ---- epilogue
  const float invl = 1.0f / lsum;
  const int bq = bh / 12, h = bh % 12;
#pragma unroll
  for (int r = 0; r < 16; ++r) {
    const int qrow = (r & 3) + 8 * (r >> 2) + 4 * hi;
    const float ir = __shfl(invl, qrow, 64);
    const int n = q0 + qrow;
    u16* dst = AO + ((size_t)bq * 1024 + n) * 768 + h * 64 + l31;
    dst[0]  = f2bf(o0[r] * ir);
    dst[32] = f2bf(o1[r] * ir);
  }
}

// ---------------------------------------------------------------- launch

extern "C" void kernel_launch(void* const* d_in, const int* in_sizes, int n_in,
                              void* d_out, int out_size, void* d_ws, size_t ws_size,
                              hipStream_t stream) {
  (void)in_sizes; (void)n_in; (void)out_size; (void)ws_size;
  const float* x    = (const float*)d_in[0];
  const float* Wqkv = (const float*)d_in[1];
  const float* s1   = (const float*)d_in[2];
  const float* sh1  = (const float*)d_in[3];
  const float* Wa   = (const float*)d_in[4];
  const float* Wb   = (const float*)d_in[5];
  const float* Wr   = (const float*)d_in[6];
  const float* brt  = (const float*)d_in[7];
  const float* Wdn  = (const float*)d_in[8];
  const float* bdn  = (const float*)d_in[9];
  const float* Wup  = (const float*)d_in[10];
  const float* bup  = (const float*)d_in[11];
  const float* Wp   = (const float*)d_in[12];
  const float* bpj  = (const float*)d_in[13];
  const float* sc2  = (const float*)d_in[14];
  const float* sf2  = (const float*)d_in[15];
  float* out = (float*)d_out;

  char* ws = (char*)d_ws;
  size_t off = 0;
  auto take = [&](size_t bytes) -> void* {
    void* p = ws + off;
    off = (off + bytes + 255) & ~(size_t)255;
    return p;
  };
  u16* Aaug = (u16*)take(8192UL * 896 * 2);
  u16* Baug = (u16*)take(2304UL * 896 * 2);
  u16* Wsm  = (u16*)take(256UL * 768 * 2);
  u16* Wpj  = (u16*)take(768UL * 768 * 2);
  float* gates = (float*)take(8192UL * 72 * 4);
  u16* qb  = (u16*)take(96UL * 1024 * 64 * 2);
  u16* kbf = (u16*)take(96UL * 1024 * 64 * 2);
  u16* vtb = (u16*)take(96UL * 64 * 1024 * 2);
  u16* ao  = (u16*)take(8192UL * 768 * 2);

  prep_x<<<dim3(6144), dim3(256), 0, stream>>>(x, Aaug);
  prep_w<<<dim3(11136), dim3(256), 0, stream>>>(Wqkv, s1, Wb, Wup, Wa, Wdn, Wr, Wp,
                                                Baug, Wsm, Wpj);
  gemm_mfma<0><<<dim3(64, 2), dim3(256), 0, stream>>>(
      Aaug, 896, Wsm, 768, bdn, brt, nullptr, Aaug, nullptr, nullptr, gates, nullptr);
  gemm_mfma<2><<<dim3(64, 18), dim3(256), 0, stream>>>(
      Aaug, 896, Baug, 896, sh1, bup, nullptr, qb, kbf, vtb, nullptr, gates);
  attn2_kernel<<<dim3(768), dim3(256), 0, stream>>>(qb, kbf, vtb, ao);
  gemm_mfma<1><<<dim3(64, 6), dim3(256), 0, stream>>>(
      ao, 768, Wpj, 768, bpj, sc2, sf2, nullptr, nullptr, nullptr, out, nullptr);
}

// Round 6
// 174.006 us; speedup vs baseline: 1.3238x; 1.1660x over previous
//
#include <hip/hip_runtime.h>
#include <math.h>

typedef unsigned short u16;
typedef unsigned int u32;
typedef short s16x8 __attribute__((ext_vector_type(8)));
typedef float f32x4 __attribute__((ext_vector_type(4)));
typedef float f32x16 __attribute__((ext_vector_type(16)));
typedef u16 u16x4 __attribute__((ext_vector_type(4)));

#define DEVI __device__ __forceinline__

DEVI u16 f2bf(float f) {
  unsigned u = __builtin_bit_cast(unsigned, f);
  u += 0x7fffu + ((u >> 16) & 1u);
  return (u16)(u >> 16);
}

// pack two f32 -> 2x bf16 with round-half-up (+0x8000) via one v_perm_b32
DEVI u32 pkbf_hu(float a, float b) {
  const u32 ua = __builtin_bit_cast(u32, a) + 0x8000u;
  const u32 ub = __builtin_bit_cast(u32, b) + 0x8000u;
  return __builtin_amdgcn_perm(ub, ua, 0x07060302u);
}

DEVI f32x4 zero4() { f32x4 z; z[0]=0.f; z[1]=0.f; z[2]=0.f; z[3]=0.f; return z; }

DEVI float xor32_max(float x) { return fmaxf(x, __shfl_xor(x, 32, 64)); }
DEVI float xor32_sum(float x) { return x + __shfl_xor(x, 32, 64); }

#define MFMA16(a,b,c) __builtin_amdgcn_mfma_f32_16x16x32_bf16((a),(b),(c),0,0,0)
#define MFMA32(a,b,c) __builtin_amdgcn_mfma_f32_32x32x16_bf16((a),(b),(c),0,0,0)

#define GLD16(gp, lp) __builtin_amdgcn_global_load_lds( \
  (const __attribute__((address_space(1))) void*)(const void*)(gp), \
  (__attribute__((address_space(3))) void*)(void*)(lp), 16, 0, 0)

#define WAITVM(N) asm volatile("s_waitcnt vmcnt(" #N ")" ::: "memory")
#define WAITLG0() asm volatile("s_waitcnt lgkmcnt(0)" ::: "memory")
#define SBAR() __builtin_amdgcn_s_barrier()

// ---------------------------------------------------------------- prep kernels

__global__ __launch_bounds__(256) void prep_x(const float* __restrict__ x,
                                              u16* __restrict__ Aaug) {
  const int i = blockIdx.x * 256 + threadIdx.x;
  if (i >= 8192 * 192) return;
  const int row = i / 192, c4 = (i - row * 192) * 4;
  const float4 v = *(const float4*)(x + (size_t)row * 768 + c4);
  u16x4 o; o[0]=f2bf(v.x); o[1]=f2bf(v.y); o[2]=f2bf(v.z); o[3]=f2bf(v.w);
  *(u16x4*)(Aaug + (size_t)row * 896 + c4) = o;
}

__global__ __launch_bounds__(256) void prep_w(
    const float* __restrict__ Wqkv, const float* __restrict__ s1,
    const float* __restrict__ Wb, const float* __restrict__ Wup,
    const float* __restrict__ Wa, const float* __restrict__ Wdn,
    const float* __restrict__ Wr, const float* __restrict__ Wp,
    u16* __restrict__ Baug, u16* __restrict__ Wsm, u16* __restrict__ Wpj) {
  const int i = blockIdx.x * 256 + threadIdx.x;
  const int N1 = 2304 * 896, N2 = N1 + 256 * 768, N3 = N2 + 768 * 768;
  if (i < N1) {
    const int c = i / 896, kk = i - c * 896;
    float v;
    if (kk < 768)      v = Wqkv[(size_t)c * 768 + kk] * s1[c];
    else if (kk < 832) v = Wb[(size_t)c * 64 + (kk - 768)];
    else               v = Wup[(size_t)c * 64 + (kk - 832)];
    Baug[i] = f2bf(v);
  } else if (i < N2) {
    const int j = i - N1; const int r = j / 768, kk = j - r * 768;
    float v = 0.0f;
    if (r < 64)       v = Wa[(size_t)r * 768 + kk];
    else if (r < 128) v = Wdn[(size_t)(r - 64) * 768 + kk];
    else if (r < 200) v = Wr[(size_t)(r - 128) * 768 + kk];
    Wsm[j] = f2bf(v);
  } else if (i < N3) {
    const int j = i - N2;
    Wpj[j] = f2bf(Wp[j]);
  }
}

// ---------------------------------------------------------------- GEMM kernel
// 3-buffer, prefetch depth-2, counted vmcnt (no full drain in main loop).

template <int MODE>
__global__ __launch_bounds__(256)
void gemm_mfma(const u16* __restrict__ A, int lda,
               const u16* __restrict__ Bt, int ldb,
               const float* __restrict__ p0, const float* __restrict__ p1,
               const float* __restrict__ p2,
               u16* __restrict__ ob0, u16* __restrict__ ob1, u16* __restrict__ ob2,
               float* __restrict__ of0,
               const float* __restrict__ gates) {
  __shared__ __align__(16) u16 lds[3][8192];
  __shared__ float glds[2][2][128];
  const int tid = threadIdx.x;
  const int w = tid >> 6, l = tid & 63;
  const int rl = l & 15, gq = l >> 4;
  const int wrow = (w >> 1) * 64, wcol = (w & 1) * 64;
  const int br = blockIdx.x, bc = blockIdx.y;
  const int nt = (MODE == 2) ? 28 : 24;

  const int srow = l >> 2;
  const int sslot = (l & 3) ^ ((srow >> 1) & 3);
  const u16* aSrc = A + (size_t)(br * 128 + w * 32 + srow) * lda + sslot * 8;
  const u16* bSrc = Bt + (size_t)(bc * 128 + w * 32 + srow) * ldb + sslot * 8;

  int tq = 0;
  if constexpr (MODE == 2) {
    const int g = bc * 2 + (w & 1);
    tq = g / 12;
  }

  auto kt_of = [&](int t) {
    if constexpr (MODE == 2) return (t < 2) ? 26 + t : ((t < 4) ? 22 + t : t - 4);
    else return t;
  };
  auto stage = [&](int kt, int buf) {
    const size_t k0 = (size_t)kt * 32;
    GLD16(aSrc + k0, &lds[buf][(w * 32) * 32]);
    GLD16(aSrc + k0 + (size_t)16 * lda, &lds[buf][(w * 32 + 16) * 32]);
    GLD16(bSrc + k0, &lds[buf][4096 + (w * 32) * 32]);
    GLD16(bSrc + k0 + (size_t)16 * ldb, &lds[buf][4096 + (w * 32 + 16) * 32]);
  };

  // prologue: stage 2 tiles, gate loads (MODE2)
  stage(kt_of(0), 0);
  stage(kt_of(1), 1);
  if constexpr (MODE == 2) {
    const int gsel = tid >> 7, rr = tid & 127;
    const int gg = bc * 2 + gsel;
    const int tt = gg / 12, hh = gg % 12;
    const int f = hh * 3 + tt;
    const int ridx = (f / 12) * 24 + (f % 12) * 2;
    glds[gsel][0][rr] = gates[(size_t)(br * 128 + rr) * 72 + ridx];
    glds[gsel][1][rr] = gates[(size_t)(br * 128 + rr) * 72 + ridx + 1];
    WAITLG0();  // glds ds_writes visible before first barrier
  }

  f32x4 acc[4][4];
#pragma unroll
  for (int i = 0; i < 4; ++i)
#pragma unroll
    for (int j = 0; j < 4; ++j) acc[i][j] = zero4();

  for (int t = 0; t < nt; ++t) {
    const int buf = t % 3;
    if (t + 2 < nt) stage(kt_of(t + 2), (t + 2) % 3);
    if (t < nt - 2)       WAITVM(8);   // tile t drained; t+1,t+2 in flight
    else if (t == nt - 2) WAITVM(4);
    else                  WAITVM(0);
    SBAR();

    const int sl = gq ^ ((rl >> 1) & 3);
    s16x8 af[4], bfv[4];
#pragma unroll
    for (int fr = 0; fr < 4; ++fr) {
      const int row = wrow + fr * 16 + rl;
      af[fr] = *(const s16x8*)&lds[buf][row * 32 + sl * 8];
    }
#pragma unroll
    for (int fc = 0; fc < 4; ++fc) {
      const int row = wcol + fc * 16 + rl;
      bfv[fc] = *(const s16x8*)&lds[buf][4096 + row * 32 + sl * 8];
    }
#pragma unroll
    for (int fr = 0; fr < 4; ++fr)
#pragma unroll
      for (int fc = 0; fc < 4; ++fc)
        acc[fr][fc] = MFMA16(af[fr], bfv[fc], acc[fr][fc]);

    if constexpr (MODE == 2) {
      if (t == 1 || t == 3) {
        const int wsel = w & 1;
        const bool ad = (t == 1);
#pragma unroll
        for (int fr = 0; fr < 4; ++fr)
#pragma unroll
          for (int r = 0; r < 4; ++r) {
            const int rloc = wrow + fr * 16 + gq * 4 + r;
            const float gl = glds[wsel][0][rloc];
            float s;
            if (ad) { const float gp = glds[wsel][1][rloc]; s = (tq > 0) ? gp / gl : 0.0f; }
            else s = gl;
#pragma unroll
            for (int fc = 0; fc < 4; ++fc) acc[fr][fc][r] *= s;
          }
      }
    }
    SBAR();  // all waves done reading lds[buf] before it is restaged
  }

  if constexpr (MODE == 0) {
#pragma unroll
    for (int fc = 0; fc < 4; ++fc) {
      const int col = bc * 128 + wcol + fc * 16 + rl;
#pragma unroll
      for (int fr = 0; fr < 4; ++fr)
#pragma unroll
        for (int r = 0; r < 4; ++r) {
          const int grow = br * 128 + wrow + fr * 16 + gq * 4 + r;
          const float v = acc[fr][fc][r];
          if (col < 64) {
            ob0[(size_t)grow * 896 + 768 + col] = f2bf(v);
          } else if (col < 128) {
            const float u = v + p0[col - 64];
            const float gv = 0.5f * u * (1.0f + erff(u * 0.70710678118654752f));
            ob0[(size_t)grow * 896 + 832 + (col - 64)] = f2bf(gv);
          } else if (col < 200) {
            const float z = v + p1[col - 128];
            of0[(size_t)grow * 72 + (col - 128)] = 1.0f / (1.0f + expf(-z));
          }
        }
    }
  } else if constexpr (MODE == 1) {
#pragma unroll
    for (int fc = 0; fc < 4; ++fc) {
      const int col = bc * 128 + wcol + fc * 16 + rl;
      const float bb = p0[col], sc = p1[col], sf = p2[col];
#pragma unroll
      for (int fr = 0; fr < 4; ++fr)
#pragma unroll
        for (int r = 0; r < 4; ++r) {
          const int grow = br * 128 + wrow + fr * 16 + gq * 4 + r;
          of0[(size_t)grow * 768 + col] = (acc[fr][fc][r] + bb) * sc + sf;
        }
    }
  } else {
    const int wsel = w & 1;
    const int bq = br >> 3;
    const int n0 = (br & 7) * 128;
    const int cbase = bc * 128 + wcol;
    const int hh = (cbase % 768) / 64;
    float s1v[4], buv[4];
#pragma unroll
    for (int fc = 0; fc < 4; ++fc) {
      const int col = cbase + fc * 16 + rl;
      s1v[fc] = p0[col];
      buv[fc] = (tq > 0) ? p1[col] : 0.0f;
    }
    if (tq < 2) {
      u16* L = (u16*)&lds[0][0] + (size_t)w * 4096;
      u16* dst = (tq == 0) ? ob0 : ob1;
      const float osc = (tq == 0) ? 0.125f : 1.0f;
#pragma unroll
      for (int fr = 0; fr < 4; ++fr)
#pragma unroll
        for (int r = 0; r < 4; ++r) {
          const int nloc = fr * 16 + gq * 4 + r;
          const float gp = glds[wsel][1][wrow + nloc];
#pragma unroll
          for (int fc = 0; fc < 4; ++fc) {
            const int d = fc * 16 + rl;
            const float v = (acc[fr][fc][r] + s1v[fc] + gp * buv[fc]) * osc;
            L[nloc * 64 + (d ^ (gq << 4))] = f2bf(v);
          }
        }
      const size_t rowbase = (size_t)(bq * 12 + hh) * 1024 + n0 + wrow;
#pragma unroll
      for (int it = 0; it < 8; ++it) {
        const int nloc = it * 8 + (l >> 3);
        const int sl8 = l & 7;
        const s16x8 val =
            *(const s16x8*)&L[nloc * 64 + ((sl8 * 8) ^ (((nloc >> 2) & 3) << 4))];
        *(s16x8*)(dst + (rowbase + nloc) * 64 + sl8 * 8) = val;
      }
    } else {
      u16* L = (u16*)&lds[0][0] + (size_t)w * 4096;
#pragma unroll
      for (int fr = 0; fr < 4; ++fr)
#pragma unroll
        for (int r = 0; r < 4; ++r) {
          const int rloc = wrow + fr * 16 + gq * 4 + r;
          const float gp = glds[wsel][1][rloc];
          const int nloc = fr * 16 + gq * 4 + r;
#pragma unroll
          for (int fc = 0; fc < 4; ++fc) {
            const int d = fc * 16 + rl;
            const float v = acc[fr][fc][r] + s1v[fc] + gp * buv[fc];
            L[(d * 64 + nloc) ^ ((d & 7) << 3)] = f2bf(v);
          }
        }
      const int nw = n0 + wrow;
#pragma unroll
      for (int it = 0; it < 8; ++it) {
        const int d = it * 8 + (l >> 3);
        const int slot = l & 7;
        const s16x8 val = *(const s16x8*)&L[d * 64 + ((slot ^ (d & 7)) << 3)];
        *(s16x8*)(ob2 + ((size_t)(bq * 12 + hh) * 64 + d) * 1024 + nw + slot * 8) = val;
      }
    }
  }
}

// ---------------------------------------------------------------- attention
// Swapped-QK^T 32x32; 3-buffer depth-2 counted-vmcnt pipeline.

__global__ __launch_bounds__(256)
void attn2_kernel(const u16* __restrict__ Q, const u16* __restrict__ K,
                  const u16* __restrict__ VT, u16* __restrict__ AO) {
  __shared__ __align__(16) u16 kv[3][8192];  // [buf][ K 64x64 | VT 64x64 ]
  const int tid = threadIdx.x, w = tid >> 6, l = tid & 63;
  const int l31 = l & 31, hi = l >> 5;
  const int bh = blockIdx.x % 96, qt = blockIdx.x / 96;
  const size_t kb = (size_t)bh * (1024 * 64);
  const float LOG2E = 1.4426950408889634f;
  const float THR = 5.545177f;

  const int q0 = qt * 128 + w * 32;
  s16x8 qf[4];
  {
    const u16* qp = Q + kb + (size_t)(q0 + l31) * 64 + hi * 8;
#pragma unroll
    for (int ks = 0; ks < 4; ++ks) qf[ks] = *(const s16x8*)(qp + ks * 16);
  }

  const int srow = l >> 3;
  const int sslot = (l & 7) ^ srow;
  const u16* kSrc = K + kb + (size_t)(w * 16 + srow) * 64 + sslot * 8;
  const u16* vSrc = VT + kb + (size_t)(w * 16 + srow) * 1024 + sslot * 8;
  auto stage = [&](int t, int buf) {
    const int kv0 = t * 64;
    GLD16(kSrc + (size_t)kv0 * 64, &kv[buf][(w * 16) * 64]);
    GLD16(kSrc + (size_t)kv0 * 64 + 8 * 64, &kv[buf][(w * 16 + 8) * 64]);
    GLD16(vSrc + kv0, &kv[buf][4096 + (w * 16) * 64]);
    GLD16(vSrc + kv0 + 8 * 1024, &kv[buf][4096 + (w * 16 + 8) * 64]);
  };

  f32x16 o0, o1;
#pragma unroll
  for (int r = 0; r < 16; ++r) { o0[r] = 0.f; o1[r] = 0.f; }
  float m = -1.0e30f, lsum = 0.f;

  const int swz = l31 & 7;

  stage(0, 0);
  stage(1, 1);

  for (int t = 0; t < 16; ++t) {
    const int buf = t % 3;
    if (t + 2 < 16) stage(t + 2, (t + 2) % 3);
    if (t < 14)       WAITVM(8);
    else if (t == 14) WAITVM(4);
    else              WAITVM(0);
    SBAR();

    // ---- QK^T: S^T[kv][q]; lane q-col = l31; kv(r,hi) = (r&3)+8*(r>>2)+4*hi
    f32x16 sA, sB;
#pragma unroll
    for (int r = 0; r < 16; ++r) { sA[r] = 0.f; sB[r] = 0.f; }
#pragma unroll
    for (int ks = 0; ks < 4; ++ks) {
      const int slot = (ks * 2 + hi) ^ swz;
      const s16x8 k0 = *(const s16x8*)&kv[buf][l31 * 64 + slot * 8];
      const s16x8 k1 = *(const s16x8*)&kv[buf][(32 + l31) * 64 + slot * 8];
      sA = MFMA32(k0, qf[ks], sA);
      sB = MFMA32(k1, qf[ks], sB);
    }

    // ---- online softmax (per-lane: one q = l31)
    float pm = sA[0];
#pragma unroll
    for (int r = 1; r < 16; ++r) pm = fmaxf(pm, sA[r]);
#pragma unroll
    for (int r = 0; r < 16; ++r) pm = fmaxf(pm, sB[r]);
    pm = xor32_max(pm);

    const bool need = pm > m + THR;
    if (__any(need)) {
      const float mnew = need ? pm : m;
      const float corr = __builtin_amdgcn_exp2f((m - mnew) * LOG2E);
      m = mnew;
      lsum *= corr;
#pragma unroll
      for (int r = 0; r < 16; ++r) {
        const int qrow = (r & 3) + 8 * (r >> 2) + 4 * hi;
        const float cr = __shfl(corr, qrow, 64);
        o0[r] *= cr; o1[r] *= cr;
      }
    }

    const float mL = m * LOG2E;
    float ps = 0.f;
#pragma unroll
    for (int r = 0; r < 16; ++r) {
      const float p = __builtin_amdgcn_exp2f(__builtin_fmaf(sA[r], LOG2E, -mL));
      sA[r] = p; ps += p;
    }
#pragma unroll
    for (int r = 0; r < 16; ++r) {
      const float p = __builtin_amdgcn_exp2f(__builtin_fmaf(sB[r], LOG2E, -mL));
      sB[r] = p; ps += p;
    }
    lsum += xor32_sum(ps);

    // ---- P -> bf16 A-fragments via perm-pack + shfl_xor(32) + per-half select
    s16x8 pf[4];
#pragma unroll
    for (int s = 0; s < 4; ++s) {
      const f32x16 P = (s < 2) ? sA : sB;
      const int b = 8 * (s & 1);
      const u32 A0 = pkbf_hu(P[b + 0], P[b + 1]);
      const u32 A1 = pkbf_hu(P[b + 2], P[b + 3]);
      const u32 A2 = pkbf_hu(P[b + 4], P[b + 5]);
      const u32 A3 = pkbf_hu(P[b + 6], P[b + 7]);
      const u32 B0 = (u32)__shfl_xor((int)A0, 32, 64);
      const u32 B1 = (u32)__shfl_xor((int)A1, 32, 64);
      const u32 B2 = (u32)__shfl_xor((int)A2, 32, 64);
      const u32 B3 = (u32)__shfl_xor((int)A3, 32, 64);
      union { u32 u[4]; s16x8 v; } pk;
      pk.u[0] = hi ? B2 : A0;
      pk.u[1] = hi ? B3 : A1;
      pk.u[2] = hi ? A2 : B0;
      pk.u[3] = hi ? A3 : B1;
      pf[s] = pk.v;
    }

    // ---- PV
#pragma unroll
    for (int s = 0; s < 4; ++s) {
      const int slot = (s * 2 + hi) ^ swz;
      const s16x8 v0 = *(const s16x8*)&kv[buf][4096 + l31 * 64 + slot * 8];
      const s16x8 v1 = *(const s16x8*)&kv[buf][4096 + (32 + l31) * 64 + slot * 8];
      o0 = MFMA32(pf[s], v0, o0);
      o1 = MFMA32(pf[s], v1, o1);
    }
    SBAR();
  }

  // ---- epilogue
  const float invl = 1.0f / lsum;
  const int bq = bh / 12, h = bh % 12;
#pragma unroll
  for (int r = 0; r < 16; ++r) {
    const int qrow = (r & 3) + 8 * (r >> 2) + 4 * hi;
    const float ir = __shfl(invl, qrow, 64);
    const int n = q0 + qrow;
    u16* dst = AO + ((size_t)bq * 1024 + n) * 768 + h * 64 + l31;
    dst[0]  = f2bf(o0[r] * ir);
    dst[32] = f2bf(o1[r] * ir);
  }
}

// ---------------------------------------------------------------- launch

extern "C" void kernel_launch(void* const* d_in, const int* in_sizes, int n_in,
                              void* d_out, int out_size, void* d_ws, size_t ws_size,
                              hipStream_t stream) {
  (void)in_sizes; (void)n_in; (void)out_size; (void)ws_size;
  const float* x    = (const float*)d_in[0];
  const float* Wqkv = (const float*)d_in[1];
  const float* s1   = (const float*)d_in[2];
  const float* sh1  = (const float*)d_in[3];
  const float* Wa   = (const float*)d_in[4];
  const float* Wb   = (const float*)d_in[5];
  const float* Wr   = (const float*)d_in[6];
  const float* brt  = (const float*)d_in[7];
  const float* Wdn  = (const float*)d_in[8];
  const float* bdn  = (const float*)d_in[9];
  const float* Wup  = (const float*)d_in[10];
  const float* bup  = (const float*)d_in[11];
  const float* Wp   = (const float*)d_in[12];
  const float* bpj  = (const float*)d_in[13];
  const float* sc2  = (const float*)d_in[14];
  const float* sf2  = (const float*)d_in[15];
  float* out = (float*)d_out;

  char* ws = (char*)d_ws;
  size_t off = 0;
  auto take = [&](size_t bytes) -> void* {
    void* p = ws + off;
    off = (off + bytes + 255) & ~(size_t)255;
    return p;
  };
  u16* Aaug = (u16*)take(8192UL * 896 * 2);
  u16* Baug = (u16*)take(2304UL * 896 * 2);
  u16* Wsm  = (u16*)take(256UL * 768 * 2);
  u16* Wpj  = (u16*)take(768UL * 768 * 2);
  float* gates = (float*)take(8192UL * 72 * 4);
  u16* qb  = (u16*)take(96UL * 1024 * 64 * 2);
  u16* kbf = (u16*)take(96UL * 1024 * 64 * 2);
  u16* vtb = (u16*)take(96UL * 64 * 1024 * 2);
  u16* ao  = (u16*)take(8192UL * 768 * 2);

  prep_x<<<dim3(6144), dim3(256), 0, stream>>>(x, Aaug);
  prep_w<<<dim3(11136), dim3(256), 0, stream>>>(Wqkv, s1, Wb, Wup, Wa, Wdn, Wr, Wp,
                                                Baug, Wsm, Wpj);
  gemm_mfma<0><<<dim3(64, 2), dim3(256), 0, stream>>>(
      Aaug, 896, Wsm, 768, bdn, brt, nullptr, Aaug, nullptr, nullptr, gates, nullptr);
  gemm_mfma<2><<<dim3(64, 18), dim3(256), 0, stream>>>(
      Aaug, 896, Baug, 896, sh1, bup, nullptr, qb, kbf, vtb, nullptr, gates);
  attn2_kernel<<<dim3(768), dim3(256), 0, stream>>>(qb, kbf, vtb, ao);
  gemm_mfma<1><<<dim3(64, 6), dim3(256), 0, stream>>>(
      ao, 768, Wpj, 768, bpj, sc2, sf2, nullptr, nullptr, nullptr, out, nullptr);
}